// Round 14
// baseline (259.082 us; speedup 1.0000x reference)
//
#include <hip/hip_runtime.h>

// DeepAttention: h = tanh([attn@ctx, x] @ Wout^T-ish), attn = softmax(mask(w . relu(ctx@W^T)))
// R14: k_logits v9 — MLP via occupancy: 256-thr blocks (4 waves, 1/SIMD), launch_bounds(256,3)
// -> 3 blocks/CU = 12 waves/CU (no spill; cap ~170 vs natural ~140). Depth-2 xA/xB rotation.
// bf16-PV + single-bf16 W (validated absmax-neutral). grid (16,BB)=2048 blocks.

#define BB 128
#define SS 8192
#define DD 128

typedef float f32x4_t __attribute__((ext_vector_type(4)));
typedef short bf16x8_t __attribute__((ext_vector_type(8)));
typedef unsigned short u16x8_t __attribute__((ext_vector_type(8)));
typedef unsigned int u32x4_t __attribute__((ext_vector_type(4)));
typedef int i32x4_t __attribute__((ext_vector_type(4)));

__device__ __forceinline__ unsigned short f2bf(float x) {
  unsigned u = __builtin_bit_cast(unsigned, x);
  unsigned r = (u + 0x7FFFu + ((u >> 16) & 1u)) >> 16;
  return (unsigned short)r;
}
// hw pack: low16 = bf16(a), high16 = bf16(b)  (RNE)
__device__ __forceinline__ unsigned cvtpk(float a, float b) {
  unsigned r;
  asm("v_cvt_pk_bf16_f32 %0, %1, %2" : "=v"(r) : "v"(a), "v"(b));
  return r;
}

// ---- K1: detect mask format (all 256 blocks) + prep (blocks < 128).
__global__ void k_prep(const unsigned int* __restrict__ mw, unsigned int* __restrict__ flag,
                       const float* __restrict__ inp, const float* __restrict__ Wg,
                       const float* __restrict__ Vg, unsigned short* __restrict__ Whi,
                       float* __restrict__ wv) {
  const int b = blockIdx.x, tid = threadIdx.x;    // 256 blocks x 256 thr
  {
    unsigned v = mw[b * 256 + tid];               // first 256 KB of mask
    unsigned f = 0;
    if (v == 0x3F800000u) f = 2u;
    else if (v > 1u) f = 1u;
    if (f) atomicOr(flag, f);
  }
  __shared__ float xin[DD];
  if (b < BB) {
    if (tid < DD) {
      int i = b * DD + tid;
      Whi[i] = f2bf(Wg[i]);
      xin[tid] = inp[b * DD + tid];
    }
    __syncthreads();
    if (tid < DD) {
      const float* wr = Wg + tid * DD;
      float s = 0.f;
#pragma unroll 8
      for (int d = 0; d < DD; ++d) s += xin[d] * wr[d];
      wv[b * DD + tid] = fmaxf(s, 0.f) * Vg[tid];
    }
  }
}

// ---- K2 v9: fused logits + mask + online-softmax weighted accumulation ----
// grid (16, BB), 256 thr (4 waves). Wave owns 128 rows = 8 tiles of 16.
// Depth-2 register rotation (xA/xB): 2 tiles = 16 KB per wave in flight.
__launch_bounds__(256, 3)
__global__ void k_logits(const float* __restrict__ ctx, const unsigned short* __restrict__ Whi,
                         const float* __restrict__ wv, const void* __restrict__ maskp,
                         const unsigned int* __restrict__ flag, float* __restrict__ logits,
                         float* __restrict__ Wslice, float* __restrict__ stats) {
  __shared__ unsigned short WPKH[16384];     // 32 KB: W, fragment-packed
  __shared__ float wl[DD];
  __shared__ float WB[4][DD];                // per-wave weighted vectors
  __shared__ float MS[4][2];                 // per-wave (m, s)

  const int tid = threadIdx.x;
  const int b = blockIdx.y;
  const int slice = blockIdx.x;              // 0..15, 512 rows each
  const int wave = tid >> 6;
  const int lane = tid & 63;
  const int lr = lane & 15;
  const int lg = lane >> 4;
  const unsigned mode = *flag;

  const long rowb0 = (long)b * SS + (long)slice * 512 + (long)wave * 128;

  f32x4_t xA[8], xB[8];                      // two 16-row tile buffers (32 VGPR each)
  auto issue = [&](f32x4_t (&x)[8], int t) {
    const float* rp = ctx + (rowb0 + t * 16 + lr) * (long)DD + lg * 8;
#pragma unroll
    for (int ks = 0; ks < 4; ++ks) {
      x[ks * 2]     = *(const f32x4_t*)(rp + ks * 32);
      x[ks * 2 + 1] = *(const f32x4_t*)(rp + ks * 32 + 4);
    }
  };

  issue(xA, 0);                              // tiles 0,1 fly under W staging
  issue(xB, 1);

  // Stage W into packed-fragment layout. Packed unit p (16B) = frag p>>6, lane p&63.
#pragma unroll
  for (int jj = 0; jj < 8; ++jj) {
    int p = tid + jj * 256;                  // 2048 units
    int frag = p >> 6;                       // et*4 + ks
    int li = p & 63;
    int et = frag >> 2, ks = frag & 3;
    int lg2 = li >> 4, lr2 = li & 15;
    int src = (et * 16 + lr2) * DD + ks * 32 + lg2 * 8;
    *(u16x8_t*)(&WPKH[p * 8]) = *(const u16x8_t*)(&Whi[src]);
  }
  if (tid < DD) wl[tid] = wv[b * DD + tid];
  __syncthreads();

  float wfreg[8];
#pragma unroll
  for (int et = 0; et < 8; ++et) wfreg[et] = wl[et * 16 + lr];

  float m_run = -3.4e38f, s_run = 0.f;
  f32x4_t wacc[8];
#pragma unroll
  for (int k = 0; k < 8; ++k) wacc[k] = f32x4_t{0.f, 0.f, 0.f, 0.f};

  const int srcl = (lane & 12) << 2;
  const int sel = lane & 3;

  auto process = [&](f32x4_t (&x)[8], int t, int tpre) {
    // ---- convert x -> bf16 A-frags (waits loads; frees x) ----
    bf16x8_t a[4];
#pragma unroll
    for (int ks = 0; ks < 4; ++ks) {
      f32x4_t x0 = x[ks * 2], x1 = x[ks * 2 + 1];
      u32x4_t hh;
      hh[0] = cvtpk(x0[0], x0[1]);
      hh[1] = cvtpk(x0[2], x0[3]);
      hh[2] = cvtpk(x1[0], x1[1]);
      hh[3] = cvtpk(x1[2], x1[3]);
      a[ks] = __builtin_bit_cast(bf16x8_t, hh);
    }
    if (tpre < 8) issue(x, tpre);            // refill this buffer 2 tiles ahead

    // ---- logits: 8 et-tiles, 32 MFMA ----
    f32x4_t part = {0.f, 0.f, 0.f, 0.f};
#pragma unroll
    for (int et = 0; et < 8; ++et) {
      f32x4_t v = {0.f, 0.f, 0.f, 0.f};
#pragma unroll
      for (int ks = 0; ks < 4; ++ks) {
        const int pidx = ((((et << 2) | ks) << 6) | lane) << 3;
        bf16x8_t bh = *(const bf16x8_t*)(&WPKH[pidx]);
        v = __builtin_amdgcn_mfma_f32_16x16x32_bf16(a[ks], bh, v, 0, 0, 0);
      }
      const float wf = wfreg[et];
#pragma unroll
      for (int i = 0; i < 4; ++i)
        part[i] += wf * fmaxf(v[i], 0.f);
    }
    // ---- sum over e: butterfly across the 16 lr lanes ----
#pragma unroll
    for (int m2 = 1; m2 < 16; m2 <<= 1) {
      part[0] += __shfl_xor(part[0], m2, 64);
      part[1] += __shfl_xor(part[1], m2, 64);
      part[2] += __shfl_xor(part[2], m2, 64);
      part[3] += __shfl_xor(part[3], m2, 64);
    }
    // ---- mask rows rowb..rowb+3, store masked logits ----
    const long rowb = rowb0 + t * 16 + lg * 4;
    bool mk0, mk1, mk2, mk3;
    if (mode == 0) {
      i32x4_t mv = *(const i32x4_t*)((const int*)maskp + rowb);
      mk0 = mv[0] != 0; mk1 = mv[1] != 0; mk2 = mv[2] != 0; mk3 = mv[3] != 0;
    } else if (mode == 1) {
      unsigned mb = *(const unsigned*)((const unsigned char*)maskp + rowb);
      mk0 = (mb & 255u) != 0; mk1 = ((mb >> 8) & 255u) != 0;
      mk2 = ((mb >> 16) & 255u) != 0; mk3 = (mb >> 24) != 0;
    } else {
      f32x4_t mf = *(const f32x4_t*)((const float*)maskp + rowb);
      mk0 = mf[0] != 0.f; mk1 = mf[1] != 0.f; mk2 = mf[2] != 0.f; mk3 = mf[3] != 0.f;
    }
    part[0] = mk0 ? -1e12f : part[0];
    part[1] = mk1 ? -1e12f : part[1];
    part[2] = mk2 ? -1e12f : part[2];
    part[3] = mk3 ? -1e12f : part[3];
    if (lr == 0) *(f32x4_t*)(&logits[rowb]) = part;
    // ---- online softmax (wave-shared max) ----
    float gm = fmaxf(fmaxf(part[0], part[1]), fmaxf(part[2], part[3]));
    gm = fmaxf(gm, __shfl_xor(gm, 16, 64));
    gm = fmaxf(gm, __shfl_xor(gm, 32, 64));
    if (gm > m_run) {
      float sc = expf(m_run - gm);
      s_run *= sc;
#pragma unroll
      for (int k = 0; k < 8; ++k) {
        wacc[k][0] *= sc; wacc[k][1] *= sc; wacc[k][2] *= sc; wacc[k][3] *= sc;
      }
      m_run = gm;
    }
    float pv0 = expf(part[0] - m_run);
    float pv1 = expf(part[1] - m_run);
    float pv2 = expf(part[2] - m_run);
    float pv3 = expf(part[3] - m_run);
    s_run += (pv0 + pv1) + (pv2 + pv3);
    // permute p to ctx-holder lanes (holder lr's row: src lane (lr>>2)*16, comp lr&3)
    float q0 = __shfl(pv0, srcl, 64);
    float q1 = __shfl(pv1, srcl, 64);
    float q2 = __shfl(pv2, srcl, 64);
    float q3 = __shfl(pv3, srcl, 64);
    float pn = sel == 0 ? q0 : sel == 1 ? q1 : sel == 2 ? q2 : q3;
    // ---- weighted accumulate from unpacked bf16 A-frags ----
#pragma unroll
    for (int ks = 0; ks < 4; ++ks) {
      u32x4_t u = __builtin_bit_cast(u32x4_t, a[ks]);
#pragma unroll
      for (int j = 0; j < 4; ++j) {
        float flo = __builtin_bit_cast(float, u[j] << 16);
        float fhi = __builtin_bit_cast(float, u[j] & 0xFFFF0000u);
        wacc[ks * 2 + (j >> 1)][(j & 1) * 2 + 0] += pn * flo;
        wacc[ks * 2 + (j >> 1)][(j & 1) * 2 + 1] += pn * fhi;
      }
    }
  };

  // 8 tiles, depth-2 rotation: buffer refilled 2 tiles ahead
#pragma unroll 1
  for (int tt = 0; tt < 4; ++tt) {
    process(xA, tt * 2,     tt * 2 + 2);
    process(xB, tt * 2 + 1, tt * 2 + 3);
  }

  // ---- wave epilogue: reduce W_acc over 16 rows (lr bits), s over lg bits ----
#pragma unroll
  for (int m2 = 1; m2 < 16; m2 <<= 1) {
#pragma unroll
    for (int k = 0; k < 8; ++k) {
      wacc[k][0] += __shfl_xor(wacc[k][0], m2, 64);
      wacc[k][1] += __shfl_xor(wacc[k][1], m2, 64);
      wacc[k][2] += __shfl_xor(wacc[k][2], m2, 64);
      wacc[k][3] += __shfl_xor(wacc[k][3], m2, 64);
    }
  }
  float st = s_run;
  st += __shfl_xor(st, 16, 64);
  st += __shfl_xor(st, 32, 64);
  if (lr == 0) {
#pragma unroll
    for (int k = 0; k < 8; ++k) {
      int ks = k >> 1, half = k & 1;
      int col = ks * 32 + lg * 8 + half * 4;
      WB[wave][col + 0] = wacc[k][0];
      WB[wave][col + 1] = wacc[k][1];
      WB[wave][col + 2] = wacc[k][2];
      WB[wave][col + 3] = wacc[k][3];
    }
  }
  if (lane == 0) { MS[wave][0] = m_run; MS[wave][1] = st; }
  __syncthreads();
  // ---- block combine across 4 waves -> per-slice (M, S, W[128]) ----
  if (tid < DD) {
    float M = fmaxf(fmaxf(MS[0][0], MS[1][0]), fmaxf(MS[2][0], MS[3][0]));
    float Wv = 0.f, S = 0.f;
#pragma unroll
    for (int w = 0; w < 4; ++w) {
      float e = expf(MS[w][0] - M);
      Wv += WB[w][tid] * e;
      S  += MS[w][1] * e;
    }
    Wslice[(long)(b * 16 + slice) * DD + tid] = Wv;
    if (tid == 0) {
      stats[(b * 16 + slice) * 2 + 0] = M;
      stats[(b * 16 + slice) * 2 + 1] = S;
    }
  }
}

// ---- K3: merged post. grid (BB, 5), 512 thr.
// y<4: normalize masked logits -> attn. y==4: combine 16 slices + tanh GEMM (tid<128).
__global__ void k_post(float* attnbuf, const float* __restrict__ stats,
                       const float* __restrict__ Wslice, const float* __restrict__ inp,
                       const float* __restrict__ Wout, float* __restrict__ hout) {
  const int b = blockIdx.x, role = blockIdx.y;
  const int tid = threadIdx.x;               // 512
  float M = -3.4e38f;
#pragma unroll
  for (int i = 0; i < 16; ++i) M = fmaxf(M, stats[b * 32 + i * 2]);
  float S = 0.f;
#pragma unroll
  for (int i = 0; i < 16; ++i) S += stats[b * 32 + i * 2 + 1] * expf(stats[b * 32 + i * 2] - M);
  if (role < 4) {
    float inv = 1.f / S;
    const long off = (long)b * SS + (long)role * 2048 + (long)tid * 4;
    f32x4_t v = *(const f32x4_t*)(attnbuf + off);
    v[0] = expf(v[0] - M) * inv;
    v[1] = expf(v[1] - M) * inv;
    v[2] = expf(v[2] - M) * inv;
    v[3] = expf(v[3] - M) * inv;
    *(f32x4_t*)(attnbuf + off) = v;
  } else {
    __shared__ float wsh[DD], xin[DD];
    if (tid < DD) {
      float Wv = 0.f;
#pragma unroll
      for (int i = 0; i < 16; ++i)
        Wv += Wslice[(long)(b * 16 + i) * DD + tid] * expf(stats[b * 32 + i * 2] - M);
      wsh[tid] = Wv / S;
      xin[tid] = inp[b * DD + tid];
    }
    __syncthreads();
    if (tid < DD) {
      const float* wr = Wout + tid * (2 * DD);
      float s = 0.f;
#pragma unroll 8
      for (int f = 0; f < DD; ++f) s += wsh[f] * wr[f];
#pragma unroll 8
      for (int f = 0; f < DD; ++f) s += xin[f] * wr[DD + f];
      hout[b * DD + tid] = tanhf(s);
    }
  }
}

extern "C" void kernel_launch(void* const* d_in, const int* in_sizes, int n_in,
                              void* d_out, int out_size, void* d_ws, size_t ws_size,
                              hipStream_t stream) {
  const float* inp  = (const float*)d_in[0];
  const float* ctx  = (const float*)d_in[1];
  const void*  mask = d_in[2];
  const float* Wg   = (const float*)d_in[3];
  const float* Vg   = (const float*)d_in[4];
  const float* Wout = (const float*)d_in[5];

  float* out = (float*)d_out;
  float* h_out = out;                 // [B, D]
  float* attn_out = out + BB * DD;    // [B, S]  (masked logits -> attn, in place)

  char* ws = (char*)d_ws;
  unsigned int*   flag   = (unsigned int*)ws;
  unsigned short* Whi    = (unsigned short*)(ws + 1024);
  float*          wv     = (float*)(ws + 1024 + 32768);
  float*          Wslice = (float*)(ws + 1024 + 32768 + 65536);             // [B][16][D] = 1 MB
  float*          stats  = (float*)(ws + 1024 + 32768 + 65536 + 1048576);   // [B][16][2] = 16 KB

  (void)hipMemsetAsync(flag, 0, 4, stream);
  k_prep  <<<dim3(256),    dim3(256), 0, stream>>>((const unsigned int*)mask, flag,
                                                   inp, Wg, Vg, Whi, wv);
  k_logits<<<dim3(16, BB), dim3(256), 0, stream>>>(ctx, Whi, wv, mask, flag,
                                                   attn_out, Wslice, stats);
  k_post  <<<dim3(BB, 5),  dim3(512), 0, stream>>>(attn_out, stats, Wslice, inp, Wout, h_out);
}

// Round 15
// 157.435 us; speedup vs baseline: 1.6456x; 1.6456x over previous
//
#include <hip/hip_runtime.h>

// DeepAttention: h = tanh([attn@ctx, x] @ Wout^T-ish), attn = softmax(mask(w . relu(ctx@W^T)))
// R15: R11-exact fused k_logits (best measured: 164.95us) + ONE change: non-temporal
// loads on the ctx stream (read-once data; no L2 allocation). hi/lo W 2-term split,
// 32-row groups sharing B-frags, single xbuf, bf16-PV.

#define BB 128
#define SS 8192
#define DD 128

typedef float f32x4_t __attribute__((ext_vector_type(4)));
typedef short bf16x8_t __attribute__((ext_vector_type(8)));
typedef unsigned short u16x8_t __attribute__((ext_vector_type(8)));
typedef unsigned int u32x4_t __attribute__((ext_vector_type(4)));
typedef int i32x4_t __attribute__((ext_vector_type(4)));

__device__ __forceinline__ unsigned short f2bf(float x) {
  unsigned u = __builtin_bit_cast(unsigned, x);
  unsigned r = (u + 0x7FFFu + ((u >> 16) & 1u)) >> 16;
  return (unsigned short)r;
}
__device__ __forceinline__ float bf2f(unsigned short h) {
  unsigned u = ((unsigned)h) << 16;
  return __builtin_bit_cast(float, u);
}
// hw pack: low16 = bf16(a), high16 = bf16(b)  (RNE)
__device__ __forceinline__ unsigned cvtpk(float a, float b) {
  unsigned r;
  asm("v_cvt_pk_bf16_f32 %0, %1, %2" : "=v"(r) : "v"(a), "v"(b));
  return r;
}

// ---- K1: detect mask format (all 256 blocks) + prep (blocks < 128).
__global__ void k_prep(const unsigned int* __restrict__ mw, unsigned int* __restrict__ flag,
                       const float* __restrict__ inp, const float* __restrict__ Wg,
                       const float* __restrict__ Vg, unsigned short* __restrict__ Whi,
                       unsigned short* __restrict__ Wlo, float* __restrict__ wv) {
  const int b = blockIdx.x, tid = threadIdx.x;    // 256 blocks x 256 thr
  {
    unsigned v = mw[b * 256 + tid];               // first 256 KB of mask
    unsigned f = 0;
    if (v == 0x3F800000u) f = 2u;
    else if (v > 1u) f = 1u;
    if (f) atomicOr(flag, f);
  }
  __shared__ float xin[DD];
  if (b < BB) {
    if (tid < DD) {
      int i = b * DD + tid;
      float x = Wg[i];
      unsigned short h = f2bf(x);
      Whi[i] = h;
      Wlo[i] = f2bf(x - bf2f(h));
      xin[tid] = inp[b * DD + tid];
    }
    __syncthreads();
    if (tid < DD) {
      const float* wr = Wg + tid * DD;
      float s = 0.f;
#pragma unroll 8
      for (int d = 0; d < DD; ++d) s += xin[d] * wr[d];
      wv[b * DD + tid] = fmaxf(s, 0.f) * Vg[tid];
    }
  }
}

// ---- K2: R11-exact fused logits + mask + online-softmax weighted accumulation ----
// grid (4, BB), 512 thr. Wave: 256 rows = 8 groups of 32 rows (2 row-tiles sharing B-frags).
// ONLY change vs R11: non-temporal ctx loads.
__launch_bounds__(512, 1)
__global__ void k_logits(const float* __restrict__ ctx, const unsigned short* __restrict__ Whi,
                         const unsigned short* __restrict__ Wlo, const float* __restrict__ wv,
                         const void* __restrict__ maskp, const unsigned int* __restrict__ flag,
                         float* __restrict__ logits, float* __restrict__ Wslice,
                         float* __restrict__ stats) {
  __shared__ unsigned short WPKH[16384];     // 32 KB: W-hi, fragment-packed
  __shared__ unsigned short WPKL[16384];     // 32 KB: W-lo
  __shared__ float wl[DD];
  __shared__ float WB[8][DD];                // per-wave weighted vectors
  __shared__ float MS[8][2];                 // per-wave (m, s)

  const int tid = threadIdx.x;
  const int b = blockIdx.y;
  const int slice = blockIdx.x;              // 0..3, 2048 rows each
  const int wave = tid >> 6;
  const int lane = tid & 63;
  const int lr = lane & 15;
  const int lg = lane >> 4;
  const unsigned mode = *flag;

  const long rowb0 = (long)b * SS + (long)slice * 2048 + (long)wave * 256;

  f32x4_t xbuf[16];                          // 32 rows of ctx (both row-tiles), 64 VGPR
  auto issue = [&](long grow) {
#pragma unroll
    for (int rt = 0; rt < 2; ++rt) {
      const float* rp = ctx + (grow + rt * 16 + lr) * (long)DD + lg * 8;
#pragma unroll
      for (int ks = 0; ks < 4; ++ks) {
        xbuf[rt * 8 + ks * 2]     = __builtin_nontemporal_load((const f32x4_t*)(rp + ks * 32));
        xbuf[rt * 8 + ks * 2 + 1] = __builtin_nontemporal_load((const f32x4_t*)(rp + ks * 32 + 4));
      }
    }
  };

  issue(rowb0);                              // group-0 loads fly under W staging

  // Stage W hi/lo into packed-fragment layout. Packed unit p (16B) = frag p>>6, lane p&63.
#pragma unroll
  for (int jj = 0; jj < 4; ++jj) {
    int p = tid + jj * 512;                  // 2048 units per array
    int frag = p >> 6;                       // et*4 + ks
    int li = p & 63;
    int et = frag >> 2, ks = frag & 3;
    int lg2 = li >> 4, lr2 = li & 15;
    int src = (et * 16 + lr2) * DD + ks * 32 + lg2 * 8;
    *(u16x8_t*)(&WPKH[p * 8]) = *(const u16x8_t*)(&Whi[src]);
    *(u16x8_t*)(&WPKL[p * 8]) = *(const u16x8_t*)(&Wlo[src]);
  }
  if (tid < DD) wl[tid] = wv[b * DD + tid];
  __syncthreads();

  float wfreg[8];
#pragma unroll
  for (int et = 0; et < 8; ++et) wfreg[et] = wl[et * 16 + lr];

  float m_run = -3.4e38f, s_run = 0.f;
  f32x4_t wacc[8];
#pragma unroll
  for (int k = 0; k < 8; ++k) wacc[k] = f32x4_t{0.f, 0.f, 0.f, 0.f};

#pragma unroll 1
  for (int g = 0; g < 8; ++g) {
    const long grow = rowb0 + (long)g * 32;
    // ---- convert xbuf -> bf16 A-frags (waits loads; frees xbuf for next issue) ----
    bf16x8_t a[2][4];
#pragma unroll
    for (int rt = 0; rt < 2; ++rt) {
#pragma unroll
      for (int ks = 0; ks < 4; ++ks) {
        f32x4_t x0 = xbuf[rt * 8 + ks * 2];
        f32x4_t x1 = xbuf[rt * 8 + ks * 2 + 1];
        u32x4_t hh;
        hh[0] = cvtpk(x0[0], x0[1]);
        hh[1] = cvtpk(x0[2], x0[3]);
        hh[2] = cvtpk(x1[0], x1[1]);
        hh[3] = cvtpk(x1[2], x1[3]);
        a[rt][ks] = __builtin_bit_cast(bf16x8_t, hh);
      }
    }
    if (g < 7) issue(grow + 32);             // prefetch next group under the MFMAs

    // ---- logits: 8 et-tiles; B-frags read ONCE, applied to both row-tiles ----
    f32x4_t part[2] = {{0.f, 0.f, 0.f, 0.f}, {0.f, 0.f, 0.f, 0.f}};
#pragma unroll
    for (int et = 0; et < 8; ++et) {
      bf16x8_t bh[4], bl[4];
#pragma unroll
      for (int ks = 0; ks < 4; ++ks) {
        const int pidx = ((((et << 2) | ks) << 6) | lane) << 3;
        bh[ks] = *(const bf16x8_t*)(&WPKH[pidx]);
        bl[ks] = *(const bf16x8_t*)(&WPKL[pidx]);
      }
      const float wf = wfreg[et];
#pragma unroll
      for (int rt = 0; rt < 2; ++rt) {
        f32x4_t v1 = {0.f, 0.f, 0.f, 0.f};
        f32x4_t v2 = v1;
#pragma unroll
        for (int ks = 0; ks < 4; ++ks) {
          v1 = __builtin_amdgcn_mfma_f32_16x16x32_bf16(a[rt][ks], bh[ks], v1, 0, 0, 0);
          v2 = __builtin_amdgcn_mfma_f32_16x16x32_bf16(a[rt][ks], bl[ks], v2, 0, 0, 0);
        }
#pragma unroll
        for (int i = 0; i < 4; ++i)
          part[rt][i] += wf * fmaxf(v1[i] + v2[i], 0.f);
      }
    }
    // ---- sum over e: butterfly across the 16 lr lanes ----
#pragma unroll
    for (int rt = 0; rt < 2; ++rt) {
#pragma unroll
      for (int m2 = 1; m2 < 16; m2 <<= 1) {
        part[rt][0] += __shfl_xor(part[rt][0], m2, 64);
        part[rt][1] += __shfl_xor(part[rt][1], m2, 64);
        part[rt][2] += __shfl_xor(part[rt][2], m2, 64);
        part[rt][3] += __shfl_xor(part[rt][3], m2, 64);
      }
    }
    // ---- mask + store masked logits ----
#pragma unroll
    for (int rt = 0; rt < 2; ++rt) {
      const long rowb = grow + rt * 16 + lg * 4;
      bool mk0, mk1, mk2, mk3;
      if (mode == 0) {
        i32x4_t mv = *(const i32x4_t*)((const int*)maskp + rowb);
        mk0 = mv[0] != 0; mk1 = mv[1] != 0; mk2 = mv[2] != 0; mk3 = mv[3] != 0;
      } else if (mode == 1) {
        unsigned mb = *(const unsigned*)((const unsigned char*)maskp + rowb);
        mk0 = (mb & 255u) != 0; mk1 = ((mb >> 8) & 255u) != 0;
        mk2 = ((mb >> 16) & 255u) != 0; mk3 = (mb >> 24) != 0;
      } else {
        f32x4_t mf = *(const f32x4_t*)((const float*)maskp + rowb);
        mk0 = mf[0] != 0.f; mk1 = mf[1] != 0.f; mk2 = mf[2] != 0.f; mk3 = mf[3] != 0.f;
      }
      part[rt][0] = mk0 ? -1e12f : part[rt][0];
      part[rt][1] = mk1 ? -1e12f : part[rt][1];
      part[rt][2] = mk2 ? -1e12f : part[rt][2];
      part[rt][3] = mk3 ? -1e12f : part[rt][3];
      if (lr == 0) *(f32x4_t*)(&logits[rowb]) = part[rt];
    }
    // ---- online softmax update (wave-shared max) ----
    float gm = fmaxf(fmaxf(fmaxf(part[0][0], part[0][1]), fmaxf(part[0][2], part[0][3])),
                     fmaxf(fmaxf(part[1][0], part[1][1]), fmaxf(part[1][2], part[1][3])));
    gm = fmaxf(gm, __shfl_xor(gm, 16, 64));
    gm = fmaxf(gm, __shfl_xor(gm, 32, 64));
    if (gm > m_run) {
      float sc = expf(m_run - gm);
      s_run *= sc;
#pragma unroll
      for (int k = 0; k < 8; ++k) {
        wacc[k][0] *= sc; wacc[k][1] *= sc; wacc[k][2] *= sc; wacc[k][3] *= sc;
      }
      m_run = gm;
    }
    const int srcl = (lane & 12) << 2;
    const int sel = lane & 3;
#pragma unroll
    for (int rt = 0; rt < 2; ++rt) {
      float pv0 = expf(part[rt][0] - m_run);
      float pv1 = expf(part[rt][1] - m_run);
      float pv2 = expf(part[rt][2] - m_run);
      float pv3 = expf(part[rt][3] - m_run);
      s_run += (pv0 + pv1) + (pv2 + pv3);
      // permute p to ctx-holder lanes (holder lr's row: src lane (lr>>2)*16, comp lr&3)
      float q0 = __shfl(pv0, srcl, 64);
      float q1 = __shfl(pv1, srcl, 64);
      float q2 = __shfl(pv2, srcl, 64);
      float q3 = __shfl(pv3, srcl, 64);
      float pn = sel == 0 ? q0 : sel == 1 ? q1 : sel == 2 ? q2 : q3;
      // accumulate weighted from unpacked bf16 A-frags (d = ks*32+lg*8 + elem)
#pragma unroll
      for (int ks = 0; ks < 4; ++ks) {
        u32x4_t u = __builtin_bit_cast(u32x4_t, a[rt][ks]);
#pragma unroll
        for (int j = 0; j < 4; ++j) {
          float flo = __builtin_bit_cast(float, u[j] << 16);
          float fhi = __builtin_bit_cast(float, u[j] & 0xFFFF0000u);
          wacc[ks * 2 + (j >> 1)][(j & 1) * 2 + 0] += pn * flo;
          wacc[ks * 2 + (j >> 1)][(j & 1) * 2 + 1] += pn * fhi;
        }
      }
    }
  }

  // ---- wave epilogue: reduce W_acc over the 16 rows (lr bits), s over lg bits ----
#pragma unroll
  for (int m2 = 1; m2 < 16; m2 <<= 1) {
#pragma unroll
    for (int k = 0; k < 8; ++k) {
      wacc[k][0] += __shfl_xor(wacc[k][0], m2, 64);
      wacc[k][1] += __shfl_xor(wacc[k][1], m2, 64);
      wacc[k][2] += __shfl_xor(wacc[k][2], m2, 64);
      wacc[k][3] += __shfl_xor(wacc[k][3], m2, 64);
    }
  }
  float st = s_run;
  st += __shfl_xor(st, 16, 64);
  st += __shfl_xor(st, 32, 64);
  if (lr == 0) {
#pragma unroll
    for (int k = 0; k < 8; ++k) {
      int ks = k >> 1, half = k & 1;
      int col = ks * 32 + lg * 8 + half * 4;
      WB[wave][col + 0] = wacc[k][0];
      WB[wave][col + 1] = wacc[k][1];
      WB[wave][col + 2] = wacc[k][2];
      WB[wave][col + 3] = wacc[k][3];
    }
  }
  if (lane == 0) { MS[wave][0] = m_run; MS[wave][1] = st; }
  __syncthreads();
  // ---- block combine across 8 waves -> per-slice (M, S, W[128]) ----
  if (tid < DD) {
    float M = MS[0][0];
#pragma unroll
    for (int w = 1; w < 8; ++w) M = fmaxf(M, MS[w][0]);
    float Wv = 0.f, S = 0.f;
#pragma unroll
    for (int w = 0; w < 8; ++w) {
      float e = expf(MS[w][0] - M);
      Wv += WB[w][tid] * e;
      S  += MS[w][1] * e;
    }
    Wslice[(long)(b * 4 + slice) * DD + tid] = Wv;
    if (tid == 0) {
      stats[(b * 4 + slice) * 2 + 0] = M;
      stats[(b * 4 + slice) * 2 + 1] = S;
    }
  }
}

// ---- K3: merged post. grid (BB, 5), 512 thr.
// y<4: normalize masked logits -> attn. y==4: combine slices + tanh GEMM (tid<128).
__global__ void k_post(float* attnbuf, const float* __restrict__ stats,
                       const float* __restrict__ Wslice, const float* __restrict__ inp,
                       const float* __restrict__ Wout, float* __restrict__ hout) {
  const int b = blockIdx.x, role = blockIdx.y;
  const int tid = threadIdx.x;               // 512
  float m0 = stats[b * 8 + 0], s0 = stats[b * 8 + 1];
  float m1 = stats[b * 8 + 2], s1 = stats[b * 8 + 3];
  float m2 = stats[b * 8 + 4], s2 = stats[b * 8 + 5];
  float m3 = stats[b * 8 + 6], s3 = stats[b * 8 + 7];
  float M = fmaxf(fmaxf(m0, m1), fmaxf(m2, m3));
  float e0 = expf(m0 - M), e1 = expf(m1 - M), e2 = expf(m2 - M), e3 = expf(m3 - M);
  float S = s0 * e0 + s1 * e1 + s2 * e2 + s3 * e3;
  if (role < 4) {
    float inv = 1.f / S;
    const long off = (long)b * SS + (long)role * 2048 + (long)tid * 4;
    f32x4_t v = *(const f32x4_t*)(attnbuf + off);
    v[0] = expf(v[0] - M) * inv;
    v[1] = expf(v[1] - M) * inv;
    v[2] = expf(v[2] - M) * inv;
    v[3] = expf(v[3] - M) * inv;
    *(f32x4_t*)(attnbuf + off) = v;
  } else {
    __shared__ float wsh[DD], xin[DD];
    if (tid < DD) {
      float Wv = Wslice[(long)(b * 4 + 0) * DD + tid] * e0
               + Wslice[(long)(b * 4 + 1) * DD + tid] * e1
               + Wslice[(long)(b * 4 + 2) * DD + tid] * e2
               + Wslice[(long)(b * 4 + 3) * DD + tid] * e3;
      wsh[tid] = Wv / S;
      xin[tid] = inp[b * DD + tid];
    }
    __syncthreads();
    if (tid < DD) {
      const float* wr = Wout + tid * (2 * DD);
      float s = 0.f;
#pragma unroll 8
      for (int f = 0; f < DD; ++f) s += wsh[f] * wr[f];
#pragma unroll 8
      for (int f = 0; f < DD; ++f) s += xin[f] * wr[DD + f];
      hout[b * DD + tid] = tanhf(s);
    }
  }
}

extern "C" void kernel_launch(void* const* d_in, const int* in_sizes, int n_in,
                              void* d_out, int out_size, void* d_ws, size_t ws_size,
                              hipStream_t stream) {
  const float* inp  = (const float*)d_in[0];
  const float* ctx  = (const float*)d_in[1];
  const void*  mask = d_in[2];
  const float* Wg   = (const float*)d_in[3];
  const float* Vg   = (const float*)d_in[4];
  const float* Wout = (const float*)d_in[5];

  float* out = (float*)d_out;
  float* h_out = out;                 // [B, D]
  float* attn_out = out + BB * DD;    // [B, S]  (masked logits -> attn, in place)

  char* ws = (char*)d_ws;
  unsigned int*   flag   = (unsigned int*)ws;
  unsigned short* Whi    = (unsigned short*)(ws + 1024);
  unsigned short* Wlo    = (unsigned short*)(ws + 1024 + 32768);
  float*          wv     = (float*)(ws + 1024 + 65536);
  float*          Wslice = (float*)(ws + 1024 + 65536 + 65536);            // [B][4][D] = 256 KB
  float*          stats  = (float*)(ws + 1024 + 65536 + 65536 + 262144);   // [B][4][2] = 4 KB

  (void)hipMemsetAsync(flag, 0, 4, stream);
  k_prep  <<<dim3(256),   dim3(256), 0, stream>>>((const unsigned int*)mask, flag,
                                                  inp, Wg, Vg, Whi, Wlo, wv);
  k_logits<<<dim3(4, BB), dim3(512), 0, stream>>>(ctx, Whi, Wlo, wv, mask, flag,
                                                  attn_out, Wslice, stats);
  k_post  <<<dim3(BB, 5), dim3(512), 0, stream>>>(attn_out, stats, Wslice, inp, Wout, h_out);
}